// Round 10
// baseline (156.079 us; speedup 1.0000x reference)
//
#include <hip/hip_runtime.h>
#include <climits>

// ---------------------------------------------------------------------------
// ChamferBoundarySDFLoss — bitwise-f32 replication of the numpy reference.
// R10: R6 (proven 90.3 µs) with k_gather+k_final fused under ALL lessons:
//   - 9216 blocks, TPG=1 (R9's 1024x9 serial loop lost parallelism)
//   - NO __threadfence (R9's per-block fence = +53 µs; R8 validated the
//     fence-free s_waitcnt + atomic-RMW-chain ordering)
//   - counters on 144 padded lines (<=64 increments each; R5's single-line
//     9216-counter was the 166 µs disaster)
//   - inject partials -> 64 padded f64 bucket lines; winner reads via
//     atomicAdd(p, 0.0) coherent RMW reads (R8-validated).
// 5 dispatches.
// ---------------------------------------------------------------------------

typedef unsigned long long ull;

constexpr int B = 4, H = 768, W = 768, K = 4096;
constexpr int HW = H * W;
constexpr int NFIELD = 2 * B;            // field f: sample f>>1, f&1: 0=pred 1=gt
constexpr int BANDS = 256;               // 3 rows per band
constexpr int WPR = W / 64;              // 12 mask words per row
constexpr int SEGW = 768 * WPR;          // words per segment (z/v/h, row-aligned)
constexpr int MSTRIDE = 3 * SEGW;        // words per field
constexpr int GSPLIT = 16;               // gt-range split for NN
constexpr int GRNG = K / GSPLIT;         // 256 gt pts per NN block
constexpr int IBLK = K / 256;            // 16 point-blocks per sample
constexpr int NDBLK = B * HW / 256;      // 9216 gather blocks
constexpr int NBKT = 64;                 // inject bucket lines (64B apart)
constexpr int NMESO = NDBLK / 64;        // 144 meso counter lines

constexpr size_t alignup(size_t x, size_t a) { return (x + a - 1) & ~(a - 1); }

// workspace layout (bytes)
constexpr size_t OFF_ACC   = 0;                                            // double[8] (4..7 = pixel)
constexpr size_t OFF_BACC  = OFF_ACC + sizeof(double) * 8;                 // double[NBKT*8]
constexpr size_t OFF_CNT   = OFF_BACC + sizeof(double) * NBKT * 8;         // int[NFIELD]
constexpr size_t OFF_MESO  = OFF_CNT + sizeof(int) * NFIELD;               // int[NMESO*16]
constexpr size_t OFF_MST   = OFF_MESO + sizeof(int) * NMESO * 16;          // int[1]
constexpr size_t OFF_WCNT  = OFF_MST + sizeof(int) * 4;                    // int[NFIELD*768]
constexpr size_t OFF_MASKS = alignup(OFF_WCNT + sizeof(int) * NFIELD * 768, 8);
constexpr size_t OFF_PTS   = OFF_MASKS + sizeof(ull) * NFIELD * MSTRIDE;   // float2[NFIELD*K]
constexpr size_t OFF_NNKEY = OFF_PTS + sizeof(float2) * NFIELD * K;        // ull[B*K]
constexpr size_t OFF_HEADS = alignup(OFF_NNKEY + sizeof(ull) * (size_t)B * K, 16);
constexpr size_t OFF_NXT   = OFF_HEADS + sizeof(int) * (size_t)B * HW;
constexpr size_t OFF_EVAL  = OFF_NXT + sizeof(int) * (size_t)B * 4 * K;
constexpr size_t OFF_DIRTY = OFF_EVAL + sizeof(float) * (size_t)B * 4 * K;
constexpr size_t WS_NEED   = OFF_DIRTY + sizeof(int) * NDBLK;              // ~8.3 MB

#define DEVFN __device__ __forceinline__

DEVFN float grad_r(const float* __restrict__ s, int r, int c) {
#pragma clang fp contract(off)
  if (r == 0)      return s[W + c] - s[c];
  if (r == H - 1)  return s[(H - 1) * W + c] - s[(H - 2) * W + c];
  return 0.5f * (s[(r + 1) * W + c] - s[(r - 1) * W + c]);
}
DEVFN float grad_c(const float* __restrict__ s, int r, int c) {
#pragma clang fp contract(off)
  if (c == 0)      return s[r * W + 1] - s[r * W];
  if (c == W - 1)  return s[r * W + W - 1] - s[r * W + W - 2];
  return 0.5f * (s[r * W + c + 1] - s[r * W + c - 1]);
}

DEVFN const float* field_sdf(const float* pred, const float* gt, int f) {
  return ((f & 1) ? gt : pred) + (size_t)(f >> 1) * HW;
}

// Row-aligned single-pass count (wave = field x 3-row band) + ALL clears.
__global__ __launch_bounds__(256) void k_count(const float* __restrict__ pred,
                                               const float* __restrict__ gt,
                                               ull* __restrict__ masks,
                                               int* __restrict__ wave_cnt,
                                               int* __restrict__ heads,
                                               int* __restrict__ dirty,
                                               ull* __restrict__ nnkey,
                                               double* __restrict__ bacc,
                                               int* __restrict__ meso,
                                               int* __restrict__ master,
                                               double* __restrict__ acc) {
#pragma clang fp contract(off)
  int gtid = blockIdx.x * 256 + (int)threadIdx.x;
  int gsz = gridDim.x * 256;
  int4* h4 = (int4*)heads;
  for (int idx = gtid; idx < B * HW / 4; idx += gsz)
    h4[idx] = make_int4(-1, -1, -1, -1);
  for (int idx = gtid; idx < NDBLK; idx += gsz) dirty[idx] = 0;
  for (int idx = gtid; idx < B * K; idx += gsz) nnkey[idx] = ~0ull;
  if (gtid < 8) acc[gtid] = 0.0;
  if (gtid >= 64 && gtid < 64 + NBKT * 8) bacc[gtid - 64] = 0.0;
  if (gtid >= 1024 && gtid < 1024 + NMESO * 16) meso[gtid - 1024] = 0;
  if (gtid == 4096) *master = 0;

  int f = blockIdx.x >> 6;                    // 64 blocks/field
  int bb = blockIdx.x & 63;
  int wave = threadIdx.x >> 6, lane = threadIdx.x & 63;
  int band = bb * 4 + wave;
  int r0 = band * 3;
  const float* sdf = field_sdf(pred, gt, f);
  ull* mz = masks + (size_t)f * MSTRIDE;
  ull* mv = mz + SEGW;
  ull* mh = mv + SEGW;

  float cur[WPR], nxt[WPR];
#pragma unroll
  for (int i = 0; i < WPR; ++i) cur[i] = sdf[r0 * W + i * 64 + lane];
  int cz = 0, cv = 0, ch = 0;
  for (int rr = 0; rr < 3; ++rr) {
    int row = r0 + rr;
    bool hasNext = row < H - 1;
    if (hasNext) {
#pragma unroll
      for (int i = 0; i < WPR; ++i) nxt[i] = sdf[(row + 1) * W + i * 64 + lane];
    }
#pragma unroll
    for (int i = 0; i < WPR; ++i) {
      ull m = __ballot(cur[i] == 0.0f);                       // z: sdf == 0
      if (lane == 0) mz[row * WPR + i] = m;
      cz += __popcll(m);
      float nb = __shfl_down(cur[i], 1);
      float nb2 = (i < WPR - 1) ? __shfl(cur[i + 1], 0) : 0.0f;
      if (lane == 63) nb = nb2;
      bool hp = (i * 64 + lane < W - 1) && (cur[i] * nb < 0.0f);  // h crossing
      m = __ballot(hp);
      if (lane == 0) mh[row * WPR + i] = m;
      ch += __popcll(m);
      if (hasNext) {
        m = __ballot(cur[i] * nxt[i] < 0.0f);                 // v crossing
        if (lane == 0) mv[row * WPR + i] = m;
        cv += __popcll(m);
      }
    }
    if (hasNext) {
#pragma unroll
      for (int i = 0; i < WPR; ++i) cur[i] = nxt[i];
    }
  }
  if (lane == 0) {
    int* wc = wave_cnt + f * 768;
    wc[0 * BANDS + band] = cz;
    wc[1 * BANDS + band] = cv;
    wc[2 * BANDS + band] = ch;
  }
}

// Ordered emit: wave = (field, seg, band); prefix over 768 per-task counts
// (z bands, v bands, h bands = reference enumeration order). Bitwise alpha.
__global__ __launch_bounds__(256) void k_emit(const float* __restrict__ pred,
                                              const float* __restrict__ gt,
                                              const ull* __restrict__ masks,
                                              const int* __restrict__ wave_cnt,
                                              float2* __restrict__ pts,
                                              int* __restrict__ counts_raw) {
#pragma clang fp contract(off)
  int f = blockIdx.x / 192;
  int tb = blockIdx.x - f * 192;
  __shared__ int cnt_s[768];
  for (int t = threadIdx.x; t < 768; t += 256) cnt_s[t] = wave_cnt[f * 768 + t];
  __syncthreads();
  int wave = threadIdx.x >> 6, lane = threadIdx.x & 63;
  int task = tb * 4 + wave;                  // 0..767
  int seg = task >> 8, band = task & 255;
  int a = 0;
  for (int idx = lane; idx < task; idx += 64) a += cnt_s[idx];
  for (int off = 32; off > 0; off >>= 1) a += __shfl_xor(a, off, 64);
  int base = a;
  if (tb == 0 && wave == 0) {
    int t2 = 0;
    for (int idx = lane; idx < 768; idx += 64) t2 += cnt_s[idx];
    for (int off = 32; off > 0; off >>= 1) t2 += __shfl_xor(t2, off, 64);
    if (lane == 0) counts_raw[f] = t2;
  }
  if (base >= K) return;
  const float* sdf = field_sdf(pred, gt, f);
  const ull* mseg = masks + (size_t)f * MSTRIDE + (size_t)seg * SEGW;
  float2* fp = pts + (size_t)f * K;
  int r0 = band * 3;
  for (int rr = 0; rr < 3; ++rr) {
    int row = r0 + rr;
    if (seg == 1 && row >= H - 1) break;     // v rows: 0..766
    for (int i = 0; i < WPR; ++i) {
      ull m = mseg[row * WPR + i];
      if (!m) continue;
      if ((m >> lane) & 1ull) {
        int c = i * 64 + lane;
        float pr, pc;
        if (seg == 0) {
          pr = (float)row; pc = (float)c;
        } else if (seg == 1) {
          float v1 = sdf[row * W + c], v2 = sdf[(row + 1) * W + c];
          float a1 = fabsf(v1), a2 = fabsf(v2);
          float alpha = a1 / ((a1 + a2) + 1e-8f);   // left-assoc, eps outside
          pr = (float)row + alpha; pc = (float)c;
        } else {
          float h1 = sdf[row * W + c], h2 = sdf[row * W + c + 1];
          float a1 = fabsf(h1), a2 = fabsf(h2);
          float alpha = a1 / ((a1 + a2) + 1e-8f);
          pr = (float)row; pc = (float)c + alpha;
        }
        int pos = base + __popcll(m & ((1ull << lane) - 1ull));
        if (pos < K) fp[pos] = make_float2(pr, pc);
      }
      base += __popcll(m);
      if (base >= K) { rr = 3; break; }      // later positions all >= K
    }
  }
}

// 1-NN over a gt sub-range: row-bbox skip + conservative sq prune, exact
// d = sqrtf((dr*dr)+(dc*dc)) for survivors, strict < = first-min. Result
// folded via atomicMin on packed (distbits<<32)|j (tie -> min j = numpy).
__global__ __launch_bounds__(256) void k_nn(const float2* __restrict__ pts,
                                            const int* __restrict__ counts_raw,
                                            ull* __restrict__ nnkey) {
#pragma clang fp contract(off)
  int b = blockIdx.x >> 8;                   // 256 blocks/sample
  int rem = blockIdx.x & 255;
  int ib = rem >> 4, ig = rem & 15;
  int tid = (int)threadIdx.x;
  int np_ = min(counts_raw[2 * b + 0], K);
  int ng  = min(counts_raw[2 * b + 1], K);
  int j0 = ig * GRNG;
  int n = min(GRNG, ng - j0);                // may be <= 0
  const float2* gp = pts + (size_t)(2 * b + 1) * K;

  __shared__ float2 tile[GRNG];
  __shared__ float smin[256], smax[256];
  float rmin = __builtin_inff(), rmax = -__builtin_inff();
  if (tid < n) {
    float2 g = gp[j0 + tid];
    tile[tid] = g;
    rmin = g.x; rmax = g.x;
  }
  smin[tid] = rmin; smax[tid] = rmax;
  __syncthreads();
  for (int s = 128; s > 0; s >>= 1) {
    if (tid < s) {
      smin[tid] = fminf(smin[tid], smin[tid + s]);
      smax[tid] = fmaxf(smax[tid], smax[tid + s]);
    }
    __syncthreads();
  }
  float gmin = smin[0] - 3.001f, gmax = smax[0] + 3.001f;

  int i = ib * 256 + tid;
  if (i >= np_ || n <= 0) return;
  float2 q = pts[(size_t)(2 * b) * K + i];
  float pr = q.x, pc = q.y;
  if (pr < gmin || pr > gmax) return;        // row-sorted runs: usually skips
  float best = __builtin_inff();
  unsigned bj = 0xffffffffu;
#pragma unroll 4
  for (int j = 0; j < n; ++j) {
    float dr = tile[j].x - pr;
    float dc = tile[j].y - pc;
    float sqf = fmaf(dr, dr, dc * dc);       // prune (slack 1e-5 >> fma delta)
    if (sqf <= 9.0001f) {
      float d = sqrtf((dr * dr) + (dc * dc));  // exact path, CR sqrt
      if (d < best) { best = d; bj = (unsigned)(j0 + j); }
    }
  }
  if (bj != 0xffffffffu)
    atomicMin(&nnkey[(size_t)b * K + i],
              ((ull)__float_as_uint(best) << 32) | bj);
}

// pixel term + chamfer scatter (kernel boundary = sync for nnkey)
__global__ __launch_bounds__(256) void k_post(const float* __restrict__ pred,
                                              const float2* __restrict__ pts,
                                              const int* __restrict__ counts_raw,
                                              const ull* __restrict__ nnkey,
                                              int* __restrict__ heads,
                                              int* __restrict__ nxt,
                                              float* __restrict__ eval,
                                              int* __restrict__ dirty,
                                              double* __restrict__ acc) {
#pragma clang fp contract(off)
  int b = blockIdx.x >> 4;
  int i = ((blockIdx.x & 15) << 8) + (int)threadIdx.x;
  const float* P = pred + (size_t)b * HW;
  int np_ = min(counts_raw[2 * b + 0], K);
  bool active = (i < np_);
  float sval = 0.0f;
  if (active) {
    ull key = nnkey[(size_t)b * K + i];
    float2 q = pts[(size_t)(2 * b) * K + i];
    float pr = q.x, pc = q.y;

    int r0 = (int)floorf(pr); r0 = r0 < 0 ? 0 : (r0 > H - 1 ? H - 1 : r0);
    int c0 = (int)floorf(pc); c0 = c0 < 0 ? 0 : (c0 > W - 1 ? W - 1 : c0);
    int r1 = (r0 + 1 > H - 1) ? H - 1 : r0 + 1;
    int c1 = (c0 + 1 > W - 1) ? W - 1 : c0 + 1;
    float ar = pr - (float)r0;
    float ac = pc - (float)c0;
    float omr = 1.0f - ar, omc = 1.0f - ac;
    float u00 = omr * omc, u01 = omr * ac, u10 = ar * omc, u11 = ar * ac;

    // pixel term: ((img*(1-ar))*(1-ac)) grouping, left-assoc (== bilinear_sample)
    float v00 = P[r0 * W + c0], v01 = P[r0 * W + c1];
    float v10 = P[r1 * W + c0], v11 = P[r1 * W + c1];
    sval = (v00 * omr) * omc + (v01 * omr) * ac + (v10 * ar) * omc + (v11 * ar) * ac;

    float best = __uint_as_float((unsigned)(key >> 32));   // ~0 -> NaN -> false
    if (best <= 3.0f) {
      const float2* gp = pts + (size_t)(2 * b + 1) * K;
      float2 g = gp[(unsigned)(key & 0xffffffffu)];
      float grA = grad_r(P, r0, c0), grB = grad_r(P, r0, c1);
      float grC = grad_r(P, r1, c0), grD = grad_r(P, r1, c1);
      float gcA = grad_c(P, r0, c0), gcB = grad_c(P, r0, c1);
      float gcC = grad_c(P, r1, c0), gcD = grad_c(P, r1, c1);
      float n_r = ((grA * u00 + grB * u01) + grC * u10) + grD * u11;
      float n_c = ((gcA * u00 + gcB * u01) + gcC * u10) + gcD * u11;
      float nn = sqrtf((n_r * n_r) + (n_c * n_c));
      float den = nn + 1e-8f;
      float nrm_r = n_r / den, nrm_c = n_c / den;
      float dr = g.x - pr, dc = g.y - pc;                  // dir_vec = gt - pred
      float dot = (dr * nrm_r) + (dc * nrm_c);
      dot = dot * 1.0f;                                    // UPDATE_SCALE
      if (dot != 0.0f) {
        int px[4] = { r0 * W + c0, r0 * W + c1, r1 * W + c0, r1 * W + c1 };
        float cv[4] = { dot * u00, dot * u01, dot * u10, dot * u11 };
        int basee = b * 4 * K;
        for (int k2 = 0; k2 < 4; ++k2) {
          int e = k2 * K + i;                              // numpy add.at order id
          eval[basee + e] = cv[k2];
          nxt[basee + e] = atomicExch(&heads[(size_t)b * HW + px[k2]], e);
          dirty[(b * HW + px[k2]) >> 8] = 1;               // idempotent store
        }
      }
    }
  }
  __shared__ double red[256];
  red[threadIdx.x] = (double)sval;
  __syncthreads();
  for (int s = 128; s > 0; s >>= 1) {
    if ((int)threadIdx.x < s) red[threadIdx.x] += red[threadIdx.x + s];
    __syncthreads();
  }
  if (threadIdx.x == 0 && red[0] != 0.0) atomicAdd(&acc[4 + b], red[0]);
}

// gather (9216 blocks, TPG=1, full parallelism) + fused final. Inject
// partials -> 64 padded f64 bucket lines. Completion: fence-free counter
// chain (R8-validated ordering): leader's s_waitcnt vmcnt(0) drains its own
// bucket RMW, then meso (144 lines x 64) -> master (144). Winner reads all
// accumulators via atomicAdd(p, 0.0) coherent RMW reads and writes out.
__global__ __launch_bounds__(256) void k_gather_final(const float* __restrict__ pred,
                                                      const int* __restrict__ heads,
                                                      const int* __restrict__ nxt,
                                                      const float* __restrict__ eval,
                                                      const int* __restrict__ dirty,
                                                      double* __restrict__ bacc,
                                                      int* __restrict__ meso,
                                                      int* __restrict__ master,
                                                      double* __restrict__ acc,
                                                      float* __restrict__ out) {
#pragma clang fp contract(off)
  int tid = (int)threadIdx.x;
  if (dirty[blockIdx.x]) {                   // uniform broadcast load
    int idx = blockIdx.x * 256 + tid;
    int b = idx / HW;
    float term = 0.0f;
    int h = heads[idx];
    if (h >= 0) {
      int base = b * 4 * K;
      float facc = 0.0f;                     // fold ascending id == np.add.at order
      int last = -1;
      for (;;) {
        int bestE = INT_MAX;
        for (int e = h; e >= 0; e = nxt[base + e])
          if (e > last && e < bestE) bestE = e;
        if (bestE == INT_MAX) break;
        facc = facc + eval[base + bestE];
        last = bestE;
      }
      term = pred[idx] * facc;               // fl(pred * dflat)
    }
    __shared__ double red[256];
    red[tid] = (double)term;
    __syncthreads();
    for (int s = 128; s > 0; s >>= 1) {
      if (tid < s) red[tid] += red[tid + s];
      __syncthreads();
    }
    if (tid == 0 && red[0] != 0.0)
      atomicAdd(&bacc[(blockIdx.x & (NBKT - 1)) * 8 + (blockIdx.x * 256 / HW)],
                red[0]);
  }
  // fence-free completion chain (leader only; no __threadfence anywhere)
  if (tid == 0) {
    asm volatile("s_waitcnt vmcnt(0)" ::: "memory");  // own bucket RMW performed
    int old = atomicAdd(&meso[(blockIdx.x >> 6) * 16], 1);   // 144 lines, 64 each
    if (old == 63) {                         // last block of this meso group
      int o2 = atomicAdd(master, 1);
      if (o2 == NMESO - 1) {                 // all 9216 blocks' adds performed
        double mi = 0.0, mp = 0.0;
        for (int k2 = 0; k2 < NBKT; ++k2)
          for (int b2 = 0; b2 < B; ++b2)
            mi += atomicAdd(&bacc[k2 * 8 + b2], 0.0);        // coherent reads
        for (int b2 = 0; b2 < B; ++b2)
          mp += atomicAdd(&acc[4 + b2], 0.0);
        out[0] = (float)(mi * 0.25 + mp * 0.25);             // W_I = W_P = 1
      }
    }
  }
}

extern "C" void kernel_launch(void* const* d_in, const int* in_sizes, int n_in,
                              void* d_out, int out_size, void* d_ws, size_t ws_size,
                              hipStream_t stream) {
  const float* pred = (const float*)d_in[0];
  const float* gt   = (const float*)d_in[1];
  float* out = (float*)d_out;
  char* ws = (char*)d_ws;

  double* acc        = (double*)(ws + OFF_ACC);
  double* bacc       = (double*)(ws + OFF_BACC);
  int*    counts_raw = (int*)(ws + OFF_CNT);
  int*    meso       = (int*)(ws + OFF_MESO);
  int*    master     = (int*)(ws + OFF_MST);
  int*    wave_cnt   = (int*)(ws + OFF_WCNT);
  ull*    masks      = (ull*)(ws + OFF_MASKS);
  float2* pts        = (float2*)(ws + OFF_PTS);
  ull*    nnkey      = (ull*)(ws + OFF_NNKEY);
  int*    heads      = (int*)(ws + OFF_HEADS);
  int*    nxt        = (int*)(ws + OFF_NXT);
  float*  eval       = (float*)(ws + OFF_EVAL);
  int*    dirty      = (int*)(ws + OFF_DIRTY);

  (void)in_sizes; (void)n_in; (void)out_size; (void)ws_size; // WS_NEED ~8.3 MB

  k_count<<<dim3(NFIELD * 64), dim3(256), 0, stream>>>(pred, gt, masks, wave_cnt,
                                                       heads, dirty, nnkey,
                                                       bacc, meso, master, acc);
  k_emit<<<dim3(NFIELD * 192), dim3(256), 0, stream>>>(pred, gt, masks, wave_cnt,
                                                       pts, counts_raw);
  k_nn<<<dim3(B * IBLK * GSPLIT), dim3(256), 0, stream>>>(pts, counts_raw, nnkey);
  k_post<<<dim3(B * IBLK), dim3(256), 0, stream>>>(pred, pts, counts_raw, nnkey,
                                                   heads, nxt, eval, dirty, acc);
  k_gather_final<<<dim3(NDBLK), dim3(256), 0, stream>>>(pred, heads, nxt, eval,
                                                        dirty, bacc, meso, master,
                                                        acc, out);
}

// Round 11
// 79.624 us; speedup vs baseline: 1.9602x; 1.9602x over previous
//
#include <hip/hip_runtime.h>
#include <climits>

// ---------------------------------------------------------------------------
// ChamferBoundarySDFLoss — bitwise-f32 replication of the numpy reference.
// R11: R6 pipeline (6 dispatches, proven 90.3 µs; every fusion attempt
// R5/R7/R8/R9/R10 regressed — serial winner tails / fences / occupancy).
// Local fixes only: per-accumulator cacheline padding, 64 padded inject
// bucket lines in k_gather (~32 same-line atomics instead of ~575), and a
// parallel-read k_final (no serial dependent RMW chain).
// ---------------------------------------------------------------------------

typedef unsigned long long ull;

constexpr int B = 4, H = 768, W = 768, K = 4096;
constexpr int HW = H * W;
constexpr int NFIELD = 2 * B;            // field f: sample f>>1, f&1: 0=pred 1=gt
constexpr int BANDS = 256;               // 3 rows per band
constexpr int WPR = W / 64;              // 12 mask words per row
constexpr int SEGW = 768 * WPR;          // words per segment (z/v/h, row-aligned)
constexpr int MSTRIDE = 3 * SEGW;        // words per field
constexpr int GSPLIT = 16;               // gt-range split for NN
constexpr int GRNG = K / GSPLIT;         // 256 gt pts per NN block
constexpr int IBLK = K / 256;            // 16 point-blocks per sample
constexpr int NDBLK = B * HW / 256;      // 9216 gather blocks
constexpr int NBKT_S = 16;               // inject bucket lines per sample

constexpr size_t alignup(size_t x, size_t a) { return (x + a - 1) & ~(a - 1); }

// workspace layout (bytes). Each accumulator padded to a 64-B line.
constexpr size_t OFF_ACCP  = 0;                                            // double[8][8]: line i = acc i (4..7 = pixel)
constexpr size_t OFF_BACC  = OFF_ACCP + sizeof(double) * 8 * 8;            // double[64][8]: inject buckets
constexpr size_t OFF_CNT   = OFF_BACC + sizeof(double) * 64 * 8;           // int[NFIELD]
constexpr size_t OFF_WCNT  = OFF_CNT + sizeof(int) * NFIELD;               // int[NFIELD*768]
constexpr size_t OFF_MASKS = alignup(OFF_WCNT + sizeof(int) * NFIELD * 768, 8);
constexpr size_t OFF_PTS   = OFF_MASKS + sizeof(ull) * NFIELD * MSTRIDE;   // float2[NFIELD*K]
constexpr size_t OFF_NNKEY = OFF_PTS + sizeof(float2) * NFIELD * K;        // ull[B*K]
constexpr size_t OFF_HEADS = alignup(OFF_NNKEY + sizeof(ull) * (size_t)B * K, 16);
constexpr size_t OFF_NXT   = OFF_HEADS + sizeof(int) * (size_t)B * HW;
constexpr size_t OFF_EVAL  = OFF_NXT + sizeof(int) * (size_t)B * 4 * K;
constexpr size_t OFF_DIRTY = OFF_EVAL + sizeof(float) * (size_t)B * 4 * K;
constexpr size_t WS_NEED   = OFF_DIRTY + sizeof(int) * NDBLK;              // ~11.8 MB

#define DEVFN __device__ __forceinline__

DEVFN float grad_r(const float* __restrict__ s, int r, int c) {
#pragma clang fp contract(off)
  if (r == 0)      return s[W + c] - s[c];
  if (r == H - 1)  return s[(H - 1) * W + c] - s[(H - 2) * W + c];
  return 0.5f * (s[(r + 1) * W + c] - s[(r - 1) * W + c]);
}
DEVFN float grad_c(const float* __restrict__ s, int r, int c) {
#pragma clang fp contract(off)
  if (c == 0)      return s[r * W + 1] - s[r * W];
  if (c == W - 1)  return s[r * W + W - 1] - s[r * W + W - 2];
  return 0.5f * (s[r * W + c + 1] - s[r * W + c - 1]);
}

DEVFN const float* field_sdf(const float* pred, const float* gt, int f) {
  return ((f & 1) ? gt : pred) + (size_t)(f >> 1) * HW;
}

// Row-aligned single-pass count (wave = field x 3-row band) + ALL clears.
__global__ __launch_bounds__(256) void k_count(const float* __restrict__ pred,
                                               const float* __restrict__ gt,
                                               ull* __restrict__ masks,
                                               int* __restrict__ wave_cnt,
                                               int* __restrict__ heads,
                                               int* __restrict__ dirty,
                                               ull* __restrict__ nnkey,
                                               double* __restrict__ bacc,
                                               double* __restrict__ accp) {
#pragma clang fp contract(off)
  int gtid = blockIdx.x * 256 + (int)threadIdx.x;
  int gsz = gridDim.x * 256;
  int4* h4 = (int4*)heads;
  for (int idx = gtid; idx < B * HW / 4; idx += gsz)
    h4[idx] = make_int4(-1, -1, -1, -1);
  for (int idx = gtid; idx < NDBLK; idx += gsz) dirty[idx] = 0;
  for (int idx = gtid; idx < B * K; idx += gsz) nnkey[idx] = ~0ull;
  if (gtid < 64) accp[gtid] = 0.0;
  if (gtid >= 64 && gtid < 64 + 512) bacc[gtid - 64] = 0.0;

  int f = blockIdx.x >> 6;                    // 64 blocks/field
  int bb = blockIdx.x & 63;
  int wave = threadIdx.x >> 6, lane = threadIdx.x & 63;
  int band = bb * 4 + wave;
  int r0 = band * 3;
  const float* sdf = field_sdf(pred, gt, f);
  ull* mz = masks + (size_t)f * MSTRIDE;
  ull* mv = mz + SEGW;
  ull* mh = mv + SEGW;

  float cur[WPR], nxt[WPR];
#pragma unroll
  for (int i = 0; i < WPR; ++i) cur[i] = sdf[r0 * W + i * 64 + lane];
  int cz = 0, cv = 0, ch = 0;
  for (int rr = 0; rr < 3; ++rr) {
    int row = r0 + rr;
    bool hasNext = row < H - 1;
    if (hasNext) {
#pragma unroll
      for (int i = 0; i < WPR; ++i) nxt[i] = sdf[(row + 1) * W + i * 64 + lane];
    }
#pragma unroll
    for (int i = 0; i < WPR; ++i) {
      ull m = __ballot(cur[i] == 0.0f);                       // z: sdf == 0
      if (lane == 0) mz[row * WPR + i] = m;
      cz += __popcll(m);
      float nb = __shfl_down(cur[i], 1);
      float nb2 = (i < WPR - 1) ? __shfl(cur[i + 1], 0) : 0.0f;
      if (lane == 63) nb = nb2;
      bool hp = (i * 64 + lane < W - 1) && (cur[i] * nb < 0.0f);  // h crossing
      m = __ballot(hp);
      if (lane == 0) mh[row * WPR + i] = m;
      ch += __popcll(m);
      if (hasNext) {
        m = __ballot(cur[i] * nxt[i] < 0.0f);                 // v crossing
        if (lane == 0) mv[row * WPR + i] = m;
        cv += __popcll(m);
      }
    }
    if (hasNext) {
#pragma unroll
      for (int i = 0; i < WPR; ++i) cur[i] = nxt[i];
    }
  }
  if (lane == 0) {
    int* wc = wave_cnt + f * 768;
    wc[0 * BANDS + band] = cz;
    wc[1 * BANDS + band] = cv;
    wc[2 * BANDS + band] = ch;
  }
}

// Ordered emit: wave = (field, seg, band); prefix over 768 per-task counts
// (z bands, v bands, h bands = reference enumeration order). Bitwise alpha.
__global__ __launch_bounds__(256) void k_emit(const float* __restrict__ pred,
                                              const float* __restrict__ gt,
                                              const ull* __restrict__ masks,
                                              const int* __restrict__ wave_cnt,
                                              float2* __restrict__ pts,
                                              int* __restrict__ counts_raw) {
#pragma clang fp contract(off)
  int f = blockIdx.x / 192;
  int tb = blockIdx.x - f * 192;
  __shared__ int cnt_s[768];
  for (int t = threadIdx.x; t < 768; t += 256) cnt_s[t] = wave_cnt[f * 768 + t];
  __syncthreads();
  int wave = threadIdx.x >> 6, lane = threadIdx.x & 63;
  int task = tb * 4 + wave;                  // 0..767
  int seg = task >> 8, band = task & 255;
  int a = 0;
  for (int idx = lane; idx < task; idx += 64) a += cnt_s[idx];
  for (int off = 32; off > 0; off >>= 1) a += __shfl_xor(a, off, 64);
  int base = a;
  if (tb == 0 && wave == 0) {
    int t2 = 0;
    for (int idx = lane; idx < 768; idx += 64) t2 += cnt_s[idx];
    for (int off = 32; off > 0; off >>= 1) t2 += __shfl_xor(t2, off, 64);
    if (lane == 0) counts_raw[f] = t2;
  }
  if (base >= K) return;
  const float* sdf = field_sdf(pred, gt, f);
  const ull* mseg = masks + (size_t)f * MSTRIDE + (size_t)seg * SEGW;
  float2* fp = pts + (size_t)f * K;
  int r0 = band * 3;
  for (int rr = 0; rr < 3; ++rr) {
    int row = r0 + rr;
    if (seg == 1 && row >= H - 1) break;     // v rows: 0..766
    for (int i = 0; i < WPR; ++i) {
      ull m = mseg[row * WPR + i];
      if (!m) continue;
      if ((m >> lane) & 1ull) {
        int c = i * 64 + lane;
        float pr, pc;
        if (seg == 0) {
          pr = (float)row; pc = (float)c;
        } else if (seg == 1) {
          float v1 = sdf[row * W + c], v2 = sdf[(row + 1) * W + c];
          float a1 = fabsf(v1), a2 = fabsf(v2);
          float alpha = a1 / ((a1 + a2) + 1e-8f);   // left-assoc, eps outside
          pr = (float)row + alpha; pc = (float)c;
        } else {
          float h1 = sdf[row * W + c], h2 = sdf[row * W + c + 1];
          float a1 = fabsf(h1), a2 = fabsf(h2);
          float alpha = a1 / ((a1 + a2) + 1e-8f);
          pr = (float)row; pc = (float)c + alpha;
        }
        int pos = base + __popcll(m & ((1ull << lane) - 1ull));
        if (pos < K) fp[pos] = make_float2(pr, pc);
      }
      base += __popcll(m);
      if (base >= K) { rr = 3; break; }      // later positions all >= K
    }
  }
}

// 1-NN over a gt sub-range: row-bbox skip + conservative sq prune, exact
// d = sqrtf((dr*dr)+(dc*dc)) for survivors, strict < = first-min. Result
// folded via atomicMin on packed (distbits<<32)|j (tie -> min j = numpy).
__global__ __launch_bounds__(256) void k_nn(const float2* __restrict__ pts,
                                            const int* __restrict__ counts_raw,
                                            ull* __restrict__ nnkey) {
#pragma clang fp contract(off)
  int b = blockIdx.x >> 8;                   // 256 blocks/sample
  int rem = blockIdx.x & 255;
  int ib = rem >> 4, ig = rem & 15;
  int tid = (int)threadIdx.x;
  int np_ = min(counts_raw[2 * b + 0], K);
  int ng  = min(counts_raw[2 * b + 1], K);
  int j0 = ig * GRNG;
  int n = min(GRNG, ng - j0);                // may be <= 0
  const float2* gp = pts + (size_t)(2 * b + 1) * K;

  __shared__ float2 tile[GRNG];
  __shared__ float smin[256], smax[256];
  float rmin = __builtin_inff(), rmax = -__builtin_inff();
  if (tid < n) {
    float2 g = gp[j0 + tid];
    tile[tid] = g;
    rmin = g.x; rmax = g.x;
  }
  smin[tid] = rmin; smax[tid] = rmax;
  __syncthreads();
  for (int s = 128; s > 0; s >>= 1) {
    if (tid < s) {
      smin[tid] = fminf(smin[tid], smin[tid + s]);
      smax[tid] = fmaxf(smax[tid], smax[tid + s]);
    }
    __syncthreads();
  }
  float gmin = smin[0] - 3.001f, gmax = smax[0] + 3.001f;

  int i = ib * 256 + tid;
  if (i >= np_ || n <= 0) return;
  float2 q = pts[(size_t)(2 * b) * K + i];
  float pr = q.x, pc = q.y;
  if (pr < gmin || pr > gmax) return;        // row-sorted runs: usually skips
  float best = __builtin_inff();
  unsigned bj = 0xffffffffu;
#pragma unroll 4
  for (int j = 0; j < n; ++j) {
    float dr = tile[j].x - pr;
    float dc = tile[j].y - pc;
    float sqf = fmaf(dr, dr, dc * dc);       // prune (slack 1e-5 >> fma delta)
    if (sqf <= 9.0001f) {
      float d = sqrtf((dr * dr) + (dc * dc));  // exact path, CR sqrt
      if (d < best) { best = d; bj = (unsigned)(j0 + j); }
    }
  }
  if (bj != 0xffffffffu)
    atomicMin(&nnkey[(size_t)b * K + i],
              ((ull)__float_as_uint(best) << 32) | bj);
}

// pixel term + chamfer scatter (kernel boundary = sync for nnkey)
__global__ __launch_bounds__(256) void k_post(const float* __restrict__ pred,
                                              const float2* __restrict__ pts,
                                              const int* __restrict__ counts_raw,
                                              const ull* __restrict__ nnkey,
                                              int* __restrict__ heads,
                                              int* __restrict__ nxt,
                                              float* __restrict__ eval,
                                              int* __restrict__ dirty,
                                              double* __restrict__ accp) {
#pragma clang fp contract(off)
  int b = blockIdx.x >> 4;
  int i = ((blockIdx.x & 15) << 8) + (int)threadIdx.x;
  const float* P = pred + (size_t)b * HW;
  int np_ = min(counts_raw[2 * b + 0], K);
  bool active = (i < np_);
  float sval = 0.0f;
  if (active) {
    ull key = nnkey[(size_t)b * K + i];
    float2 q = pts[(size_t)(2 * b) * K + i];
    float pr = q.x, pc = q.y;

    int r0 = (int)floorf(pr); r0 = r0 < 0 ? 0 : (r0 > H - 1 ? H - 1 : r0);
    int c0 = (int)floorf(pc); c0 = c0 < 0 ? 0 : (c0 > W - 1 ? W - 1 : c0);
    int r1 = (r0 + 1 > H - 1) ? H - 1 : r0 + 1;
    int c1 = (c0 + 1 > W - 1) ? W - 1 : c0 + 1;
    float ar = pr - (float)r0;
    float ac = pc - (float)c0;
    float omr = 1.0f - ar, omc = 1.0f - ac;
    float u00 = omr * omc, u01 = omr * ac, u10 = ar * omc, u11 = ar * ac;

    // pixel term: ((img*(1-ar))*(1-ac)) grouping, left-assoc (== bilinear_sample)
    float v00 = P[r0 * W + c0], v01 = P[r0 * W + c1];
    float v10 = P[r1 * W + c0], v11 = P[r1 * W + c1];
    sval = (v00 * omr) * omc + (v01 * omr) * ac + (v10 * ar) * omc + (v11 * ar) * ac;

    float best = __uint_as_float((unsigned)(key >> 32));   // ~0 -> NaN -> false
    if (best <= 3.0f) {
      const float2* gp = pts + (size_t)(2 * b + 1) * K;
      float2 g = gp[(unsigned)(key & 0xffffffffu)];
      float grA = grad_r(P, r0, c0), grB = grad_r(P, r0, c1);
      float grC = grad_r(P, r1, c0), grD = grad_r(P, r1, c1);
      float gcA = grad_c(P, r0, c0), gcB = grad_c(P, r0, c1);
      float gcC = grad_c(P, r1, c0), gcD = grad_c(P, r1, c1);
      float n_r = ((grA * u00 + grB * u01) + grC * u10) + grD * u11;
      float n_c = ((gcA * u00 + gcB * u01) + gcC * u10) + gcD * u11;
      float nn = sqrtf((n_r * n_r) + (n_c * n_c));
      float den = nn + 1e-8f;
      float nrm_r = n_r / den, nrm_c = n_c / den;
      float dr = g.x - pr, dc = g.y - pc;                  // dir_vec = gt - pred
      float dot = (dr * nrm_r) + (dc * nrm_c);
      dot = dot * 1.0f;                                    // UPDATE_SCALE
      if (dot != 0.0f) {
        int px[4] = { r0 * W + c0, r0 * W + c1, r1 * W + c0, r1 * W + c1 };
        float cv[4] = { dot * u00, dot * u01, dot * u10, dot * u11 };
        int basee = b * 4 * K;
        for (int k2 = 0; k2 < 4; ++k2) {
          int e = k2 * K + i;                              // numpy add.at order id
          eval[basee + e] = cv[k2];
          nxt[basee + e] = atomicExch(&heads[(size_t)b * HW + px[k2]], e);
          dirty[(b * HW + px[k2]) >> 8] = 1;               // idempotent store
        }
      }
    }
  }
  __shared__ double red[256];
  red[threadIdx.x] = (double)sval;
  __syncthreads();
  for (int s = 128; s > 0; s >>= 1) {
    if ((int)threadIdx.x < s) red[threadIdx.x] += red[threadIdx.x + s];
    __syncthreads();
  }
  if (threadIdx.x == 0 && red[0] != 0.0)
    atomicAdd(&accp[(4 + b) * 8], red[0]);   // padded: one line per accumulator
}

// gather: 9216 blocks, dirty early-exit; inject partials scattered over
// 16 padded bucket lines per sample (~32 same-line atomics instead of ~575).
__global__ __launch_bounds__(256) void k_gather(const float* __restrict__ pred,
                                                const int* __restrict__ heads,
                                                const int* __restrict__ nxt,
                                                const float* __restrict__ eval,
                                                const int* __restrict__ dirty,
                                                double* __restrict__ bacc) {
#pragma clang fp contract(off)
  if (!dirty[blockIdx.x]) return;            // broadcast load; ~78% of blocks
  int idx = blockIdx.x * 256 + (int)threadIdx.x;
  int b = idx / HW;
  float term = 0.0f;
  int h = heads[idx];
  if (h >= 0) {
    int base = b * 4 * K;
    float facc = 0.0f;                       // fold ascending id == np.add.at order
    int last = -1;
    for (;;) {
      int bestE = INT_MAX;
      for (int e = h; e >= 0; e = nxt[base + e])
        if (e > last && e < bestE) bestE = e;
      if (bestE == INT_MAX) break;
      facc = facc + eval[base + bestE];
      last = bestE;
    }
    term = pred[idx] * facc;                 // fl(pred * dflat)
  }
  __shared__ double red[256];
  red[threadIdx.x] = (double)term;
  __syncthreads();
  for (int s = 128; s > 0; s >>= 1) {
    if ((int)threadIdx.x < s) red[threadIdx.x] += red[threadIdx.x + s];
    __syncthreads();
  }
  if (threadIdx.x == 0 && red[0] != 0.0)
    atomicAdd(&bacc[((b << 4) | ((int)blockIdx.x & (NBKT_S - 1))) * 8], red[0]);
}

// final: 1 block x 256 threads — parallel loads (overlapped round trips,
// no serial dependent RMW chain), deterministic LDS sum, write scalar.
__global__ __launch_bounds__(256) void k_final(const double* __restrict__ bacc,
                                               const double* __restrict__ accp,
                                               float* __restrict__ out) {
  __shared__ double sv[72];
  int tid = (int)threadIdx.x;
  if (tid < 64) sv[tid] = bacc[tid * 8];             // inject buckets
  else if (tid < 72) sv[tid] = accp[(tid - 64) * 8]; // acc lines (68..71 = pixel)
  __syncthreads();
  if (tid == 0) {
    double mi = 0.0, mp = 0.0;
    for (int s = 0; s < 4; ++s) {
      for (int k2 = 0; k2 < NBKT_S; ++k2) mi += sv[s * NBKT_S + k2];
      mp += sv[64 + 4 + s];
    }
    out[0] = (float)(mi * 0.25 + mp * 0.25);         // W_INJECT = W_PIXEL = 1
  }
}

extern "C" void kernel_launch(void* const* d_in, const int* in_sizes, int n_in,
                              void* d_out, int out_size, void* d_ws, size_t ws_size,
                              hipStream_t stream) {
  const float* pred = (const float*)d_in[0];
  const float* gt   = (const float*)d_in[1];
  float* out = (float*)d_out;
  char* ws = (char*)d_ws;

  double* accp       = (double*)(ws + OFF_ACCP);
  double* bacc       = (double*)(ws + OFF_BACC);
  int*    counts_raw = (int*)(ws + OFF_CNT);
  int*    wave_cnt   = (int*)(ws + OFF_WCNT);
  ull*    masks      = (ull*)(ws + OFF_MASKS);
  float2* pts        = (float2*)(ws + OFF_PTS);
  ull*    nnkey      = (ull*)(ws + OFF_NNKEY);
  int*    heads      = (int*)(ws + OFF_HEADS);
  int*    nxt        = (int*)(ws + OFF_NXT);
  float*  eval       = (float*)(ws + OFF_EVAL);
  int*    dirty      = (int*)(ws + OFF_DIRTY);

  (void)in_sizes; (void)n_in; (void)out_size; (void)ws_size; // WS_NEED ~11.8 MB

  k_count<<<dim3(NFIELD * 64), dim3(256), 0, stream>>>(pred, gt, masks, wave_cnt,
                                                       heads, dirty, nnkey,
                                                       bacc, accp);
  k_emit<<<dim3(NFIELD * 192), dim3(256), 0, stream>>>(pred, gt, masks, wave_cnt,
                                                       pts, counts_raw);
  k_nn<<<dim3(B * IBLK * GSPLIT), dim3(256), 0, stream>>>(pts, counts_raw, nnkey);
  k_post<<<dim3(B * IBLK), dim3(256), 0, stream>>>(pred, pts, counts_raw, nnkey,
                                                   heads, nxt, eval, dirty, accp);
  k_gather<<<dim3(NDBLK), dim3(256), 0, stream>>>(pred, heads, nxt, eval, dirty,
                                                  bacc);
  k_final<<<dim3(1), dim3(256), 0, stream>>>(bacc, accp, out);
}